// Round 14
// baseline (53.042 us; speedup 1.0000x reference)
//
#include <hip/hip_runtime.h>
#include <math.h>

#define BB 32
#define TT 1024
#define FF 128
#define DD 64
#define NCLS 11
constexpr float kEps = 1e-3f;
constexpr int M = BB * TT;  // 32768 rows

typedef __attribute__((ext_vector_type(8))) short short8v;
typedef __attribute__((ext_vector_type(4))) short short4v;
typedef __attribute__((ext_vector_type(4))) float float4v;
typedef __attribute__((ext_vector_type(16))) float float16v;

__device__ __forceinline__ short f2bf(float f) {
  union { float f; unsigned u; } v; v.f = f;
  return (short)((v.u + 0x7FFFu + ((v.u >> 16) & 1u)) >> 16);
}
__device__ __forceinline__ float bf2f(short s) {
  union { unsigned u; float f; } v; v.u = ((unsigned)(unsigned short)s) << 16;
  return v.f;
}

// pack 8 fp32 -> one 32x32 PV A-frag (8 bf16) via cvt_pk + permlane32_swap.
__device__ __forceinline__ short8v pack_swap(
    float p0, float p1, float p2, float p3,
    float p4, float p5, float p6, float p7) {
  unsigned a0, a1, b0, b1;
  asm("v_cvt_pk_bf16_f32 %0, %1, %2" : "=v"(a0) : "v"(p0), "v"(p1));
  asm("v_cvt_pk_bf16_f32 %0, %1, %2" : "=v"(a1) : "v"(p2), "v"(p3));
  asm("v_cvt_pk_bf16_f32 %0, %1, %2" : "=v"(b0) : "v"(p4), "v"(p5));
  asm("v_cvt_pk_bf16_f32 %0, %1, %2" : "=v"(b1) : "v"(p6), "v"(p7));
  asm volatile("v_permlane32_swap_b32 %0, %1" : "+v"(a0), "+v"(b0));
  asm volatile("v_permlane32_swap_b32 %0, %1" : "+v"(a1), "+v"(b1));
  union { unsigned u[4]; short8v s; } r;
  r.u[0] = a0; r.u[1] = a1; r.u[2] = b0; r.u[3] = b1;
  return r.s;
}

// ---- prep: blk 0 folds; 1-4 wT4; 5-196 pe@{wq,wk,wv}; 197+ x->bf16 ----
__global__ __launch_bounds__(256) void prep_kernel(
    const float* __restrict__ x,
    const float* __restrict__ wq, const float* __restrict__ wk,
    const float* __restrict__ wv, const float* __restrict__ w1,
    const float* __restrict__ w0, const float* __restrict__ b0,
    const float* __restrict__ bn_a_gamma, const float* __restrict__ bn_a_beta,
    const float* __restrict__ bn_a_mean, const float* __restrict__ bn_a_var,
    const float* __restrict__ bn1_gamma, const float* __restrict__ bn1_beta,
    const float* __restrict__ bn1_mean, const float* __restrict__ bn1_var,
    const float* __restrict__ wd, const float* __restrict__ bd,
    short* __restrict__ xbf, short* __restrict__ wT4,
    short* __restrict__ w0pT, float* __restrict__ b0p,
    short* __restrict__ wdpT, float* __restrict__ bdp,
    float* __restrict__ peq, float* __restrict__ pek, float* __restrict__ pev) {
  const int t = threadIdx.x;
  const int blk = blockIdx.x;

  if (blk >= 197) {                  // ---- x -> bf16 (row-major copy)
    const int p2 = blk - 197;        // 0..255
    const size_t base = (size_t)p2 * 16384;
#pragma unroll
    for (int i = 0; i < 8; ++i) {
      const size_t e0 = base + (size_t)i * 2048 + (size_t)t * 8;
      const float4 a = *(const float4*)&x[e0];
      const float4 b = *(const float4*)&x[e0 + 4];
      short8v s8;
      s8[0] = f2bf(a.x); s8[1] = f2bf(a.y); s8[2] = f2bf(a.z); s8[3] = f2bf(a.w);
      s8[4] = f2bf(b.x); s8[5] = f2bf(b.y); s8[6] = f2bf(b.z); s8[7] = f2bf(b.w);
      *(short8v*)&xbf[e0] = s8;
    }
    return;
  }
  if (blk >= 5) {                    // ---- pe projection, pe rows on the fly
    __shared__ float peL[16][128];
    const int p = blk - 5;           // 0..191
    const int y = p >> 6;            // 0,1,2
    const int t0 = (p & 63) * 16;
#pragma unroll
    for (int i = 0; i < 8; ++i) {
      const int idx = t + i * 256;   // 0..2047
      const int tr = idx >> 7, f = idx & 127;
      const float div = expf(-logf(10000.0f) * (float)(f & ~1) / (float)FF);
      const float ang = (float)(t0 + tr) * div;
      peL[tr][f] = (f & 1) ? cosf(ang) : sinf(ang);
    }
    __syncthreads();
    const float* w = (y == 0) ? wq : (y == 1) ? wk : wv;
    float* dst = (y == 0) ? peq : (y == 1) ? pek : pev;
    const int tr = t >> 4, dq = t & 15;
    float4 acc = {0.f, 0.f, 0.f, 0.f};
    for (int f = 0; f < FF; ++f) {
      const float pv = peL[tr][f];
      const float4 w4 = *(const float4*)&w[f * 64 + dq * 4];
      acc.x += pv * w4.x; acc.y += pv * w4.y;
      acc.z += pv * w4.z; acc.w += pv * w4.w;
    }
    *(float4*)&dst[(t0 + tr) * 64 + dq * 4] = acc;
    return;
  }
  if (blk > 0) {                     // ---- wT4 staging image
    const int y = blk - 1;
    const float* w = (y == 0) ? wq : (y == 1) ? wk : (y == 2) ? wv : w1;
    short* dst = wT4 + y * 8192;
#pragma unroll
    for (int i = 0; i < 4; ++i) {
      const int idx = t + i * 256;   // 0..1023
      const int n = idx >> 4, c = idx & 15;
      short8v s8;
#pragma unroll
      for (int j = 0; j < 8; ++j) s8[j] = f2bf(w[(c * 8 + j) * 64 + n]);
      *(short8v*)&dst[n * 128 + ((c ^ (n & 7)) << 3)] = s8;
    }
    return;
  }
  // ---- block 0: head folds
  __shared__ float cA[64], cAo[64], c1s[64], c1o[64], c2s[64], c2o[64];
  if (t < 64) {
    const float sA = bn_a_gamma[t] * rsqrtf(bn_a_var[t] + kEps);
    cA[t] = sA; cAo[t] = bn_a_beta[t] - bn_a_mean[t] * sA;
    const float s1 = bn1_gamma[t] * rsqrtf(bn1_var[t] + kEps);
    c1s[t] = s1; c1o[t] = bn1_beta[t] - bn1_mean[t] * s1;
    const float s2 = bn1_gamma[t + 64] * rsqrtf(bn1_var[t + 64] + kEps);
    c2s[t] = s2; c2o[t] = bn1_beta[t + 64] - bn1_mean[t + 64] * s2;
  }
  __syncthreads();
  for (int i = t; i < 4096; i += 256) {
    const int e = i >> 6, k = i & 63;
    w0pT[i] = f2bf(cA[k] * w0[k * 64 + e]);
  }
  if (t < 64) {
    float s = b0[t];
    for (int k = 0; k < 64; ++k) s += cAo[k] * w0[k * 64 + t];
    b0p[t] = s;
  }
  for (int i = t; i < 2048; i += 256) {
    const int c = i >> 7, e = i & 127;
    float v = 0.f;
    if (c < NCLS) v = wd[e * NCLS + c] * (e < 64 ? c1s[e] : c2s[e - 64]);
    wdpT[i] = f2bf(v);
  }
  if (t < 16) {
    float s = 0.f;
    if (t < NCLS) {
      s = bd[t];
      for (int e = 0; e < 64; ++e) s += c1o[e] * wd[e * NCLS + t];
      for (int e = 0; e < 64; ++e) s += c2o[e] * wd[(64 + e) * NCLS + t];
    }
    bdp[t] = s;
  }
}

// --------------------- QKV + out2 projections (bf16 MFMA) --------------
// x pre-converted to bf16 (xbf); staging is pure int4 copies.
// q gets the attention exp scale folded in: q *= log2(e)/8.
__global__ __launch_bounds__(256) void proj_kernel(
    const short* __restrict__ xbf, const short* __restrict__ wT4,
    const float* __restrict__ peq, const float* __restrict__ pek,
    const float* __restrict__ pev, const float* __restrict__ b1,
    short* __restrict__ qo, short* __restrict__ ko,
    short* __restrict__ vt, short* __restrict__ o2) {
  __shared__ __align__(16) short xs[128 * 128];   // [row][k], chunk-swizzled
  __shared__ __align__(16) short wsh[64 * 128];   // [n][k], chunk-swizzled
  const int tid = threadIdx.x;
  const int lane = tid & 63;
  const int wv4 = tid >> 6;
  const int l15 = lane & 15;
  const int lg = lane >> 4;
  const int r0 = blockIdx.x * 128;
  const int y = blockIdx.y;

#pragma unroll
  for (int i = 0; i < 8; ++i) {
    int id = tid + i * 256;          // 0..2047
    int row = id >> 4, chunk = id & 15;
    const int4 v = *(const int4*)&xbf[((size_t)(r0 + row)) * FF + chunk * 8];
    *(int4*)&xs[row * 128 + ((chunk ^ (row & 7)) << 3)] = v;
  }
#pragma unroll
  for (int i = 0; i < 4; ++i) {
    const int idx = tid + i * 256;   // 1024 int4 = 16 KB
    *(int4*)&wsh[idx * 8] = *(const int4*)&wT4[y * 8192 + idx * 8];
  }
  __syncthreads();

  float4v acc[2][4];
#pragma unroll
  for (int rt = 0; rt < 2; ++rt)
#pragma unroll
    for (int dt = 0; dt < 4; ++dt) acc[rt][dt] = (float4v)0.0f;

  const bool natural = (y == 2);
#pragma unroll
  for (int kt = 0; kt < 4; ++kt) {
    const int chunk = kt * 4 + lg;
    short8v xa[2], wa[4];
#pragma unroll
    for (int rt = 0; rt < 2; ++rt) {
      const int row = wv4 * 32 + rt * 16 + l15;
      xa[rt] = *(const short8v*)&xs[row * 128 + ((chunk ^ (row & 7)) << 3)];
    }
#pragma unroll
    for (int dt = 0; dt < 4; ++dt) {
      const int n = dt * 16 + l15;
      wa[dt] = *(const short8v*)&wsh[n * 128 + ((chunk ^ (n & 7)) << 3)];
    }
#pragma unroll
    for (int rt = 0; rt < 2; ++rt)
#pragma unroll
      for (int dt = 0; dt < 4; ++dt)
        acc[rt][dt] = natural
            ? __builtin_amdgcn_mfma_f32_16x16x32_bf16(xa[rt], wa[dt], acc[rt][dt], 0, 0, 0)
            : __builtin_amdgcn_mfma_f32_16x16x32_bf16(wa[dt], xa[rt], acc[rt][dt], 0, 0, 0);
  }

  if (natural) {
    const int bq = r0 >> 10;
    const int tb = (r0 & 1023) + wv4 * 32;
#pragma unroll
    for (int rt = 0; rt < 2; ++rt) {
#pragma unroll
      for (int dt = 0; dt < 4; ++dt) {
        const int d = dt * 16 + l15;
        const int t0 = tb + rt * 16 + lg * 4;
        short4v s;
#pragma unroll
        for (int r = 0; r < 4; ++r)
          s[r] = f2bf(acc[rt][dt][r] + pev[(t0 + r) * 64 + d]);
        *(short4v*)&vt[((size_t)(bq * DD + d)) * TT + t0] = s;
      }
    }
  } else {
    short* dst = (y == 0) ? qo : (y == 1) ? ko : o2;
    const float* petab = (y == 0) ? peq : pek;
    const float qs = (y == 0) ? 0.18033688f : 1.0f;   // log2(e)/8 folded into q
#pragma unroll
    for (int rt = 0; rt < 2; ++rt) {
      const int row = r0 + wv4 * 32 + rt * 16 + l15;
      const int tr = row & 1023;
#pragma unroll
      for (int dt = 0; dt < 4; ++dt) {
        const int d0 = dt * 16 + lg * 4;
        float v0 = acc[rt][dt][0], v1 = acc[rt][dt][1];
        float v2 = acc[rt][dt][2], v3 = acc[rt][dt][3];
        if (y == 3) {
          const float4 bv = *(const float4*)&b1[d0];
          v0 = fmaxf(v0 + bv.x, 0.f); v1 = fmaxf(v1 + bv.y, 0.f);
          v2 = fmaxf(v2 + bv.z, 0.f); v3 = fmaxf(v3 + bv.w, 0.f);
        } else {
          const float4 pv = *(const float4*)&petab[tr * 64 + d0];
          v0 = (v0 + pv.x) * qs; v1 = (v1 + pv.y) * qs;
          v2 = (v2 + pv.z) * qs; v3 = (v3 + pv.w) * qs;
        }
        short4v s;
        s[0] = f2bf(v0); s[1] = f2bf(v1); s[2] = f2bf(v2); s[3] = f2bf(v3);
        *(short4v*)&dst[(size_t)row * DD + d0] = s;
      }
    }
  }
}

// --- fused attn + head, 32x32 MFMA, in-register P, 4-way kv-split -------
// Register-slimmed R12: exp in place, kf/vf loaded singly -> target <=128
// VGPR so __launch_bounds__(512,4) holds without spill (2 blocks/CU).
// Block: 512 thr = 2 q-waves (32 rows) x 4 kv-groups (8 tiles of KVBLK=32).
// LDS 64KB. Grid 512, XCD-pinned: bb = id&31.
__global__ __launch_bounds__(512, 4) void attn_head_kernel(
    const short* __restrict__ qg, const short* __restrict__ kg,
    const short* __restrict__ vtg, const short* __restrict__ o2m,
    const short* __restrict__ w0pT, const float* __restrict__ b0p,
    const short* __restrict__ wdpT, const float* __restrict__ bdp,
    float* __restrict__ out) {
  __shared__ __align__(16) char LB[65536];
  const int tid = threadIdx.x;
  const int lane = tid & 63;
  const int wid = tid >> 6;          // 0..7
  const int qwv = wid & 1;           // q-wave 0,1
  const int grp = wid >> 1;          // kv-group 0..3
  const int id = blockIdx.x;
  const int bb = id & 31;            // batch (id%8 fixes XCD)
  const int qx = id >> 5;            // 0..15
  const int l31 = lane & 31;
  const int lhi = lane >> 5;         // 0,1
  const int l15 = lane & 15;
  const int lg = lane >> 4;
  const int qbase = qx * 64 + qwv * 32;
  const int kvbase = grp * 256;      // this group's kv range (8 x 32)
  const int stid = tid & 127;

  short* const Kb[2] = {(short*)(LB + grp * 16384),
                        (short*)(LB + grp * 16384 + 4096)};
  short* const Vb[2] = {(short*)(LB + grp * 16384 + 8192),
                        (short*)(LB + grp * 16384 + 12288)};

  // staging decomposition (4 int4/thread)
  const int krow0 = stid >> 3, kc8 = (stid & 7) * 8;
  const int ksw0 = kc8 ^ ((krow0 & 7) << 3);
  const int krow1 = krow0 + 16;
  const int ksw1 = kc8 ^ ((krow1 & 7) << 3);
  const int vd0 = stid >> 2, vt4 = stid & 3;
  const int vsw0 = (vt4 ^ (vd0 & 3)) * 8;
  const int vd1 = vd0 + 32;
  const int vsw1 = (vt4 ^ (vd1 & 3)) * 8;

  // Q B-frags: lane holds Q[qbase+l31][dc*16 + lhi*8 + 0..7]
  short8v qf[4];
#pragma unroll
  for (int dc = 0; dc < 4; ++dc)
    qf[dc] = *(const short8v*)&qg[((size_t)(bb * TT + qbase + l31)) * DD + dc * 16 + lhi * 8];

  float16v oacc[2];
  oacc[0] = (float16v)0.f; oacc[1] = (float16v)0.f;
  float lacc = 0.f;

  // prologue: stage tile 0 -> buf 0
  {
    *(int4*)&Kb[0][krow0 * 64 + ksw0] =
        *(const int4*)&kg[((size_t)(bb * TT + kvbase + krow0)) * DD + kc8];
    *(int4*)&Kb[0][krow1 * 64 + ksw1] =
        *(const int4*)&kg[((size_t)(bb * TT + kvbase + krow1)) * DD + kc8];
    *(int4*)&Vb[0][vd0 * 32 + vsw0] =
        *(const int4*)&vtg[((size_t)(bb * DD + vd0)) * TT + kvbase + vt4 * 8];
    *(int4*)&Vb[0][vd1 * 32 + vsw1] =
        *(const int4*)&vtg[((size_t)(bb * DD + vd1)) * TT + kvbase + vt4 * 8];
  }
  __syncthreads();

  for (int i = 0; i < 8; ++i) {
    const int cur = i & 1;
    short* const Kc = Kb[cur];
    short* const Vc = Vb[cur];

    // issue next tile's global loads early (hide under compute)
    int4 nk0, nk1, nv0, nv1;
    if (i < 7) {
      const int nkv = kvbase + (i + 1) * 32;
      nk0 = *(const int4*)&kg[((size_t)(bb * TT + nkv + krow0)) * DD + kc8];
      nk1 = *(const int4*)&kg[((size_t)(bb * TT + nkv + krow1)) * DD + kc8];
      nv0 = *(const int4*)&vtg[((size_t)(bb * DD + vd0)) * TT + nkv + vt4 * 8];
      nv1 = *(const int4*)&vtg[((size_t)(bb * DD + vd1)) * TT + nkv + vt4 * 8];
    }

    // ---- QK^T swapped (A=K, B=Q): one 32x32 tile (kv=32); exp in place
    float16v s = (float16v)0.f;
    __builtin_amdgcn_s_setprio(1);
#pragma unroll
    for (int dc = 0; dc < 4; ++dc) {
      const int chunk = (dc * 2 + lhi) ^ (l31 & 7);
      const short8v kf = *(const short8v*)&Kc[l31 * 64 + chunk * 8];
      s = __builtin_amdgcn_mfma_f32_32x32x16_bf16(kf, qf[dc], s, 0, 0, 0);
    }
    __builtin_amdgcn_s_setprio(0);

#pragma unroll
    for (int r = 0; r < 16; ++r) { s[r] = exp2f(s[r]); lacc += s[r]; }

    const short8v pfa = pack_swap(s[0], s[1], s[2], s[3], s[4], s[5], s[6], s[7]);
    const short8v pfb = pack_swap(s[8], s[9], s[10], s[11], s[12], s[13], s[14], s[15]);

    // ---- PV: O[q][d], d halves of 32; vf loaded per-MFMA
    __builtin_amdgcn_s_setprio(1);
#pragma unroll
    for (int dh = 0; dh < 2; ++dh) {
      const int drow = dh * 32 + l31;
      const int c0 = (lhi) ^ (drow & 3);
      const short8v vf0 = *(const short8v*)&Vc[drow * 32 + c0 * 8];
      oacc[dh] = __builtin_amdgcn_mfma_f32_32x32x16_bf16(pfa, vf0, oacc[dh], 0, 0, 0);
      const int c1 = (2 + lhi) ^ (drow & 3);
      const short8v vf1 = *(const short8v*)&Vc[drow * 32 + c1 * 8];
      oacc[dh] = __builtin_amdgcn_mfma_f32_32x32x16_bf16(pfb, vf1, oacc[dh], 0, 0, 0);
    }
    __builtin_amdgcn_s_setprio(0);

    if (i < 7) {
      short* const Kn = Kb[cur ^ 1];
      short* const Vn = Vb[cur ^ 1];
      *(int4*)&Kn[krow0 * 64 + ksw0] = nk0;
      *(int4*)&Kn[krow1 * 64 + ksw1] = nk1;
      *(int4*)&Vn[vd0 * 32 + vsw0] = nv0;
      *(int4*)&Vn[vd1 * 32 + vsw1] = nv1;
      __syncthreads();
    }
  }

  // row-sum for q = l31 (complementary kv half lives in lane^32)
  lacc += __shfl_xor(lacc, 32);

  // ---- combine groups 1..3 into group 0 via LDS overlay ----
  __syncthreads();
  if (grp > 0) {
    float* cb = (float*)(LB + (grp - 1) * 16384);
#pragma unroll
    for (int dh = 0; dh < 2; ++dh)
#pragma unroll
      for (int r = 0; r < 16; ++r) {
        const int q = (r & 3) + 8 * (r >> 2) + 4 * lhi;
        cb[qwv * 2048 + q * 64 + dh * 32 + l31] = oacc[dh][r];
      }
    float* lcb = (float*)(LB + 49152);
    if (lhi == 0) lcb[(grp - 1) * 64 + qwv * 32 + l31] = lacc;
  }
  __syncthreads();
  if (grp == 0) {
#pragma unroll
    for (int g = 1; g < 4; ++g) {
      const float* cb = (const float*)(LB + (g - 1) * 16384);
#pragma unroll
      for (int dh = 0; dh < 2; ++dh)
#pragma unroll
        for (int r = 0; r < 16; ++r) {
          const int q = (r & 3) + 8 * (r >> 2) + 4 * lhi;
          oacc[dh][r] += cb[qwv * 2048 + q * 64 + dh * 32 + l31];
        }
    }
    const float* lcb = (const float*)(LB + 49152);
#pragma unroll
    for (int g = 1; g < 4; ++g) lacc += lcb[(g - 1) * 64 + qwv * 32 + l31];
    const float linv = 1.0f / lacc;        // for q = l31

    // ---- head epilogue: O -> hs [32][64] bf16 (chunk-swizzled) ----
    short* hs = (short*)(LB + 50176 + qwv * 4096);
#pragma unroll
    for (int dh = 0; dh < 2; ++dh)
#pragma unroll
      for (int r = 0; r < 16; ++r) {
        const int q = (r & 3) + 8 * (r >> 2) + 4 * lhi;
        const int d = dh * 32 + l31;
        const int chunk = d >> 3;
        hs[q * 64 + ((chunk ^ (q & 7)) << 3) + (l31 & 7)] = f2bf(oacc[dh][r]);
      }

    // two 16-row sub-blocks through the proven 16x16 head path
#pragma unroll
    for (int sub = 0; sub < 2; ++sub) {
      short* hsub = hs + sub * 16 * 64;
      short8v af[2];
#pragma unroll
      for (int dt = 0; dt < 2; ++dt) {
        const int chunk = (dt * 4 + lg) ^ (l15 & 7);
        af[dt] = *(const short8v*)&hsub[l15 * 64 + chunk * 8];
      }

      float4v acc1[4];
#pragma unroll
      for (int et = 0; et < 4; ++et) acc1[et] = (float4v)0.0f;
#pragma unroll
      for (int et = 0; et < 4; ++et)
#pragma unroll
        for (int dt = 0; dt < 2; ++dt) {
          const short8v wb = *(const short8v*)&w0pT[(et * 16 + l15) * 64 + dt * 32 + lg * 8];
          acc1[et] = __builtin_amdgcn_mfma_f32_16x16x32_bf16(af[dt], wb, acc1[et], 0, 0, 0);
        }

      float b0v[4];
#pragma unroll
      for (int et = 0; et < 4; ++et) b0v[et] = b0p[et * 16 + l15];

#pragma unroll
      for (int r = 0; r < 4; ++r) {
        const float invm = __shfl(linv, sub * 16 + lg * 4 + r);
        const int m = lg * 4 + r;
#pragma unroll
        for (int et = 0; et < 4; ++et) {
          const float v = fmaxf(acc1[et][r] * invm + b0v[et], 0.f);
          const int chunk = (et * 2 + (l15 >> 3)) ^ (m & 7);
          hsub[m * 64 + chunk * 8 + (l15 & 7)] = f2bf(v);
        }
      }

      float4v accL = (float4v)0.0f;
#pragma unroll
      for (int dt = 0; dt < 2; ++dt) {
        const int chunk = (dt * 4 + lg) ^ (l15 & 7);
        const short8v ha = *(const short8v*)&hsub[l15 * 64 + chunk * 8];
        const short8v wb = *(const short8v*)&wdpT[l15 * 128 + dt * 32 + lg * 8];
        accL = __builtin_amdgcn_mfma_f32_16x16x32_bf16(ha, wb, accL, 0, 0, 0);
      }
      const size_t o2row = ((size_t)bb * TT + qbase + sub * 16 + l15) * DD;
#pragma unroll
      for (int dt = 0; dt < 2; ++dt) {
        const short8v ha = *(const short8v*)&o2m[o2row + dt * 32 + lg * 8];
        const short8v wb = *(const short8v*)&wdpT[l15 * 128 + 64 + dt * 32 + lg * 8];
        accL = __builtin_amdgcn_mfma_f32_16x16x32_bf16(ha, wb, accL, 0, 0, 0);
      }

      const float bdv = bdp[l15];
#pragma unroll
      for (int r = 0; r < 4; ++r) {
        const float lv = (l15 < NCLS) ? (accL[r] + bdv) : -1e30f;
        float mx = lv;
#pragma unroll
        for (int off = 1; off < 16; off <<= 1) mx = fmaxf(mx, __shfl_xor(mx, off));
        const float ex = (l15 < NCLS) ? __expf(lv - mx) : 0.f;
        float sm = ex;
#pragma unroll
        for (int off = 1; off < 16; off <<= 1) sm += __shfl_xor(sm, off);
        if (l15 < NCLS)
          out[((size_t)bb * TT + qbase + sub * 16 + lg * 4 + r) * NCLS + l15] = ex / sm;
      }
    }
  }
}

// -----------------------------------------------------------------------
extern "C" void kernel_launch(void* const* d_in, const int* in_sizes, int n_in,
                              void* d_out, int out_size, void* d_ws, size_t ws_size,
                              hipStream_t stream) {
  (void)in_sizes; (void)n_in; (void)out_size; (void)ws_size;
  const float* x  = (const float*)d_in[0];
  const float* wq = (const float*)d_in[1];
  const float* wk = (const float*)d_in[2];
  const float* wv = (const float*)d_in[3];
  const float* bn_a_gamma = (const float*)d_in[4];
  const float* bn_a_beta  = (const float*)d_in[5];
  const float* bn_a_mean  = (const float*)d_in[6];
  const float* bn_a_var   = (const float*)d_in[7];
  const float* w0 = (const float*)d_in[8];
  const float* b0 = (const float*)d_in[9];
  const float* w1 = (const float*)d_in[10];
  const float* b1 = (const float*)d_in[11];
  const float* bn1_gamma = (const float*)d_in[12];
  const float* bn1_beta  = (const float*)d_in[13];
  const float* bn1_mean  = (const float*)d_in[14];
  const float* bn1_var   = (const float*)d_in[15];
  const float* wd = (const float*)d_in[16];
  const float* bd = (const float*)d_in[17];
  float* out = (float*)d_out;

  char* cur = (char*)d_ws;
  short* q  = (short*)cur; cur += (size_t)M * DD * 2;
  short* k  = (short*)cur; cur += (size_t)M * DD * 2;
  short* vt = (short*)cur; cur += (size_t)M * DD * 2;
  short* o2 = (short*)cur; cur += (size_t)M * DD * 2;
  short* xbf = (short*)cur; cur += (size_t)M * FF * 2;
  short* wT4  = (short*)cur; cur += 4 * 8192 * 2;
  short* w0pT = (short*)cur; cur += 4096 * 2;
  short* wdpT = (short*)cur; cur += 2048 * 2;
  float* b0p  = (float*)cur; cur += 64 * 4;
  float* bdp  = (float*)cur; cur += 16 * 4;
  float* peq  = (float*)cur; cur += (size_t)TT * DD * 4;
  float* pek  = (float*)cur; cur += (size_t)TT * DD * 4;
  float* pev  = (float*)cur; cur += (size_t)TT * DD * 4;

  prep_kernel<<<dim3(453), dim3(256), 0, stream>>>(
      x, wq, wk, wv, w1, w0, b0, bn_a_gamma, bn_a_beta, bn_a_mean, bn_a_var,
      bn1_gamma, bn1_beta, bn1_mean, bn1_var, wd, bd,
      xbf, wT4, w0pT, b0p, wdpT, bdp, peq, pek, pev);
  proj_kernel<<<dim3(M / 128, 4), dim3(256), 0, stream>>>(
      xbf, wT4, peq, pek, pev, b1, q, k, vt, o2);
  attn_head_kernel<<<dim3(512), dim3(512), 0, stream>>>(
      q, k, vt, o2, w0pT, b0p, wdpT, bdp, out);
}

// Round 15
// 50.262 us; speedup vs baseline: 1.0553x; 1.0553x over previous
//
#include <hip/hip_runtime.h>
#include <math.h>

#define BB 32
#define TT 1024
#define FF 128
#define DD 64
#define NCLS 11
constexpr float kEps = 1e-3f;
constexpr int M = BB * TT;  // 32768 rows

typedef __attribute__((ext_vector_type(8))) short short8v;
typedef __attribute__((ext_vector_type(4))) short short4v;
typedef __attribute__((ext_vector_type(4))) float float4v;

__device__ __forceinline__ short f2bf(float f) {
  union { float f; unsigned u; } v; v.f = f;
  return (short)((v.u + 0x7FFFu + ((v.u >> 16) & 1u)) >> 16);
}
__device__ __forceinline__ float bf2f(short s) {
  union { unsigned u; float f; } v; v.u = ((unsigned)(unsigned short)s) << 16;
  return v.f;
}

// ---- prep: blk 0 folds; 1-4 wT4; 5-196 pe@{wq,wk,wv}; 197+ x->bf16 ----
__global__ __launch_bounds__(256) void prep_kernel(
    const float* __restrict__ x,
    const float* __restrict__ wq, const float* __restrict__ wk,
    const float* __restrict__ wv, const float* __restrict__ w1,
    const float* __restrict__ w0, const float* __restrict__ b0,
    const float* __restrict__ bn_a_gamma, const float* __restrict__ bn_a_beta,
    const float* __restrict__ bn_a_mean, const float* __restrict__ bn_a_var,
    const float* __restrict__ bn1_gamma, const float* __restrict__ bn1_beta,
    const float* __restrict__ bn1_mean, const float* __restrict__ bn1_var,
    const float* __restrict__ wd, const float* __restrict__ bd,
    short* __restrict__ xbf, short* __restrict__ wT4,
    short* __restrict__ w0pT, float* __restrict__ b0p,
    short* __restrict__ wdpT, float* __restrict__ bdp,
    float* __restrict__ peq, float* __restrict__ pek, float* __restrict__ pev) {
  const int t = threadIdx.x;
  const int blk = blockIdx.x;

  if (blk >= 197) {                  // ---- x -> bf16 (row-major copy)
    const int p2 = blk - 197;        // 0..255
    const size_t base = (size_t)p2 * 16384;
#pragma unroll
    for (int i = 0; i < 8; ++i) {
      const size_t e0 = base + (size_t)i * 2048 + (size_t)t * 8;
      const float4 a = *(const float4*)&x[e0];
      const float4 b = *(const float4*)&x[e0 + 4];
      short8v s8;
      s8[0] = f2bf(a.x); s8[1] = f2bf(a.y); s8[2] = f2bf(a.z); s8[3] = f2bf(a.w);
      s8[4] = f2bf(b.x); s8[5] = f2bf(b.y); s8[6] = f2bf(b.z); s8[7] = f2bf(b.w);
      *(short8v*)&xbf[e0] = s8;
    }
    return;
  }
  if (blk >= 5) {                    // ---- pe projection, pe rows on the fly
    __shared__ float peL[16][128];
    const int p = blk - 5;           // 0..191
    const int y = p >> 6;            // 0,1,2
    const int t0 = (p & 63) * 16;
#pragma unroll
    for (int i = 0; i < 8; ++i) {
      const int idx = t + i * 256;   // 0..2047
      const int tr = idx >> 7, f = idx & 127;
      const float div = expf(-logf(10000.0f) * (float)(f & ~1) / (float)FF);
      const float ang = (float)(t0 + tr) * div;
      peL[tr][f] = (f & 1) ? cosf(ang) : sinf(ang);
    }
    __syncthreads();
    const float* w = (y == 0) ? wq : (y == 1) ? wk : wv;
    float* dst = (y == 0) ? peq : (y == 1) ? pek : pev;
    const int tr = t >> 4, dq = t & 15;
    float4 acc = {0.f, 0.f, 0.f, 0.f};
    for (int f = 0; f < FF; ++f) {
      const float pv = peL[tr][f];
      const float4 w4 = *(const float4*)&w[f * 64 + dq * 4];
      acc.x += pv * w4.x; acc.y += pv * w4.y;
      acc.z += pv * w4.z; acc.w += pv * w4.w;
    }
    *(float4*)&dst[(t0 + tr) * 64 + dq * 4] = acc;
    return;
  }
  if (blk > 0) {                     // ---- wT4 staging image
    const int y = blk - 1;
    const float* w = (y == 0) ? wq : (y == 1) ? wk : (y == 2) ? wv : w1;
    short* dst = wT4 + y * 8192;
#pragma unroll
    for (int i = 0; i < 4; ++i) {
      const int idx = t + i * 256;   // 0..1023
      const int n = idx >> 4, c = idx & 15;
      short8v s8;
#pragma unroll
      for (int j = 0; j < 8; ++j) s8[j] = f2bf(w[(c * 8 + j) * 64 + n]);
      *(short8v*)&dst[n * 128 + ((c ^ (n & 7)) << 3)] = s8;
    }
    return;
  }
  // ---- block 0: head folds
  __shared__ float cA[64], cAo[64], c1s[64], c1o[64], c2s[64], c2o[64];
  if (t < 64) {
    const float sA = bn_a_gamma[t] * rsqrtf(bn_a_var[t] + kEps);
    cA[t] = sA; cAo[t] = bn_a_beta[t] - bn_a_mean[t] * sA;
    const float s1 = bn1_gamma[t] * rsqrtf(bn1_var[t] + kEps);
    c1s[t] = s1; c1o[t] = bn1_beta[t] - bn1_mean[t] * s1;
    const float s2 = bn1_gamma[t + 64] * rsqrtf(bn1_var[t + 64] + kEps);
    c2s[t] = s2; c2o[t] = bn1_beta[t + 64] - bn1_mean[t + 64] * s2;
  }
  __syncthreads();
  for (int i = t; i < 4096; i += 256) {
    const int e = i >> 6, k = i & 63;
    w0pT[i] = f2bf(cA[k] * w0[k * 64 + e]);
  }
  if (t < 64) {
    float s = b0[t];
    for (int k = 0; k < 64; ++k) s += cAo[k] * w0[k * 64 + t];
    b0p[t] = s;
  }
  for (int i = t; i < 2048; i += 256) {
    const int c = i >> 7, e = i & 127;
    float v = 0.f;
    if (c < NCLS) v = wd[e * NCLS + c] * (e < 64 ? c1s[e] : c2s[e - 64]);
    wdpT[i] = f2bf(v);
  }
  if (t < 16) {
    float s = 0.f;
    if (t < NCLS) {
      s = bd[t];
      for (int e = 0; e < 64; ++e) s += c1o[e] * wd[e * NCLS + t];
      for (int e = 0; e < 64; ++e) s += c2o[e] * wd[(64 + e) * NCLS + t];
    }
    bdp[t] = s;
  }
}

// --------------------- QKV + out2 projections (bf16 MFMA) --------------
// x pre-converted to bf16 (xbf); staging is pure int4 copies.
// q gets the attention exp scale folded in: q *= log2(e)/8.
__global__ __launch_bounds__(256) void proj_kernel(
    const short* __restrict__ xbf, const short* __restrict__ wT4,
    const float* __restrict__ peq, const float* __restrict__ pek,
    const float* __restrict__ pev, const float* __restrict__ b1,
    short* __restrict__ qo, short* __restrict__ ko,
    short* __restrict__ vt, short* __restrict__ o2) {
  __shared__ __align__(16) short xs[128 * 128];   // [row][k], chunk-swizzled
  __shared__ __align__(16) short wsh[64 * 128];   // [n][k], chunk-swizzled
  const int tid = threadIdx.x;
  const int lane = tid & 63;
  const int wv4 = tid >> 6;
  const int l15 = lane & 15;
  const int lg = lane >> 4;
  const int r0 = blockIdx.x * 128;
  const int y = blockIdx.y;

#pragma unroll
  for (int i = 0; i < 8; ++i) {
    int id = tid + i * 256;          // 0..2047
    int row = id >> 4, chunk = id & 15;
    const int4 v = *(const int4*)&xbf[((size_t)(r0 + row)) * FF + chunk * 8];
    *(int4*)&xs[row * 128 + ((chunk ^ (row & 7)) << 3)] = v;
  }
#pragma unroll
  for (int i = 0; i < 4; ++i) {
    const int idx = tid + i * 256;   // 1024 int4 = 16 KB
    *(int4*)&wsh[idx * 8] = *(const int4*)&wT4[y * 8192 + idx * 8];
  }
  __syncthreads();

  float4v acc[2][4];
#pragma unroll
  for (int rt = 0; rt < 2; ++rt)
#pragma unroll
    for (int dt = 0; dt < 4; ++dt) acc[rt][dt] = (float4v)0.0f;

  const bool natural = (y == 2);
#pragma unroll
  for (int kt = 0; kt < 4; ++kt) {
    const int chunk = kt * 4 + lg;
    short8v xa[2], wa[4];
#pragma unroll
    for (int rt = 0; rt < 2; ++rt) {
      const int row = wv4 * 32 + rt * 16 + l15;
      xa[rt] = *(const short8v*)&xs[row * 128 + ((chunk ^ (row & 7)) << 3)];
    }
#pragma unroll
    for (int dt = 0; dt < 4; ++dt) {
      const int n = dt * 16 + l15;
      wa[dt] = *(const short8v*)&wsh[n * 128 + ((chunk ^ (n & 7)) << 3)];
    }
#pragma unroll
    for (int rt = 0; rt < 2; ++rt)
#pragma unroll
      for (int dt = 0; dt < 4; ++dt)
        acc[rt][dt] = natural
            ? __builtin_amdgcn_mfma_f32_16x16x32_bf16(xa[rt], wa[dt], acc[rt][dt], 0, 0, 0)
            : __builtin_amdgcn_mfma_f32_16x16x32_bf16(wa[dt], xa[rt], acc[rt][dt], 0, 0, 0);
  }

  if (natural) {
    const int bq = r0 >> 10;
    const int tb = (r0 & 1023) + wv4 * 32;
#pragma unroll
    for (int rt = 0; rt < 2; ++rt) {
#pragma unroll
      for (int dt = 0; dt < 4; ++dt) {
        const int d = dt * 16 + l15;
        const int t0 = tb + rt * 16 + lg * 4;
        short4v s;
#pragma unroll
        for (int r = 0; r < 4; ++r)
          s[r] = f2bf(acc[rt][dt][r] + pev[(t0 + r) * 64 + d]);
        *(short4v*)&vt[((size_t)(bq * DD + d)) * TT + t0] = s;
      }
    }
  } else {
    short* dst = (y == 0) ? qo : (y == 1) ? ko : o2;
    const float* petab = (y == 0) ? peq : pek;
    const float qs = (y == 0) ? 0.18033688f : 1.0f;   // log2(e)/8 folded into q
#pragma unroll
    for (int rt = 0; rt < 2; ++rt) {
      const int row = r0 + wv4 * 32 + rt * 16 + l15;
      const int tr = row & 1023;
#pragma unroll
      for (int dt = 0; dt < 4; ++dt) {
        const int d0 = dt * 16 + lg * 4;
        float v0 = acc[rt][dt][0], v1 = acc[rt][dt][1];
        float v2 = acc[rt][dt][2], v3 = acc[rt][dt][3];
        if (y == 3) {
          const float4 bv = *(const float4*)&b1[d0];
          v0 = fmaxf(v0 + bv.x, 0.f); v1 = fmaxf(v1 + bv.y, 0.f);
          v2 = fmaxf(v2 + bv.z, 0.f); v3 = fmaxf(v3 + bv.w, 0.f);
        } else {
          const float4 pv = *(const float4*)&petab[tr * 64 + d0];
          v0 = (v0 + pv.x) * qs; v1 = (v1 + pv.y) * qs;
          v2 = (v2 + pv.z) * qs; v3 = (v3 + pv.w) * qs;
        }
        short4v s;
        s[0] = f2bf(v0); s[1] = f2bf(v1); s[2] = f2bf(v2); s[3] = f2bf(v3);
        *(short4v*)&dst[(size_t)row * DD + d0] = s;
      }
    }
  }
}

// --- fused attn + head (R10 best structure + setprio): 8 waves, 2-group
// kv-split, dbuf staging, swapped QK^T (P row lane-local) -> packed b64 P.
// exp scale pre-folded into q. Grid 512 flat, XCD: blockIdx%8 == b%8.
__global__ __launch_bounds__(512, 4) void attn_head_kernel(
    const short* __restrict__ qg, const short* __restrict__ kg,
    const short* __restrict__ vtg, const short* __restrict__ o2m,
    const short* __restrict__ w0pT, const float* __restrict__ b0p,
    const short* __restrict__ wdpT, const float* __restrict__ bdp,
    float* __restrict__ out) {
  __shared__ __align__(16) short Ks[2][2][4096];   // [grp][dbuf][kv*d]
  __shared__ __align__(16) short Vs[2][2][4096];   // [grp][dbuf][d*kv]
  __shared__ __align__(16) short Ps[8 * 1024];     // per-wave P / hs
  const int tid = threadIdx.x;
  const int lane = tid & 63;
  const int wid = tid >> 6;          // 0..7
  const int grp = wid >> 2;          // 0,1
  const int wv = wid & 3;
  const int id = blockIdx.x;
  const int bb = (id & 7) + ((id >> 7) << 3);      // b: id%8 fixes XCD
  const int qx = (id >> 3) & 15;
  const int l15 = lane & 15;
  const int lg = lane >> 4;          // 0..3
  const int qbase = qx * 64 + wv * 16;
  const int kt0 = grp * 8;

  const int stid = tid & 255;
  const int srow0 = stid >> 3, sc8 = (stid & 7) * 8;
  const int ssw = sc8 ^ ((srow0 & 7) << 3);
  const int srow1 = srow0 + 32;
  const int ssw1 = sc8 ^ ((srow1 & 7) << 3);

  short8v qf[2];
#pragma unroll
  for (int dt = 0; dt < 2; ++dt) {
    const size_t off = ((size_t)(bb * TT + qbase + l15)) * DD + dt * 32 + lg * 8;
    qf[dt] = *(const short8v*)&qg[off];
  }
  float4v oacc[4];
#pragma unroll
  for (int dt = 0; dt < 4; ++dt) oacc[dt] = (float4v)0.0f;
  float lacc = 0.f;                  // row i = l15 partial sum

  // prologue: stage this group's tile 0 into buf 0
  {
    const int nt = kt0 * 64;
    const int4 k0 = *(const int4*)&kg[((size_t)(bb * TT + nt + srow0)) * DD + sc8];
    const int4 v0 = *(const int4*)&vtg[((size_t)(bb * DD + srow0)) * TT + nt + sc8];
    const int4 k1 = *(const int4*)&kg[((size_t)(bb * TT + nt + srow1)) * DD + sc8];
    const int4 v1 = *(const int4*)&vtg[((size_t)(bb * DD + srow1)) * TT + nt + sc8];
    *(int4*)&Ks[grp][0][srow0 * 64 + ssw] = k0;
    *(int4*)&Vs[grp][0][srow0 * 64 + ssw] = v0;
    *(int4*)&Ks[grp][0][srow1 * 64 + ssw1] = k1;
    *(int4*)&Vs[grp][0][srow1 * 64 + ssw1] = v1;
  }
  __syncthreads();

  char* const pw = (char*)&Ps[wid * 1024];   // this wave's 2KB P area
  for (int i = 0; i < 8; ++i) {
    const int cur = i & 1;

    int4 nk0, nv0, nk1, nv1;
    if (i < 7) {
      const int nt = (kt0 + i + 1) * 64;
      nk0 = *(const int4*)&kg[((size_t)(bb * TT + nt + srow0)) * DD + sc8];
      nv0 = *(const int4*)&vtg[((size_t)(bb * DD + srow0)) * TT + nt + sc8];
      nk1 = *(const int4*)&kg[((size_t)(bb * TT + nt + srow1)) * DD + sc8];
      nv1 = *(const int4*)&vtg[((size_t)(bb * DD + srow1)) * TT + nt + sc8];
    }

    // ---- QK^T swapped: A=K, B=Q -> lane holds P[i=l15][j=jt*16+lg*4+r]
    short8v kf[8];
#pragma unroll
    for (int jt = 0; jt < 4; ++jt) {
      const int j = jt * 16 + l15;
#pragma unroll
      for (int dt = 0; dt < 2; ++dt) {
        const int d0 = dt * 32 + lg * 8;
        kf[jt * 2 + dt] = *(const short8v*)&Ks[grp][cur][j * 64 + (d0 ^ ((j & 7) << 3))];
      }
    }
    float4v s2[4];
    __builtin_amdgcn_s_setprio(1);
#pragma unroll
    for (int jt = 0; jt < 4; ++jt) {
      s2[jt] = (float4v)0.0f;
      s2[jt] = __builtin_amdgcn_mfma_f32_16x16x32_bf16(kf[jt * 2 + 0], qf[0], s2[jt], 0, 0, 0);
      s2[jt] = __builtin_amdgcn_mfma_f32_16x16x32_bf16(kf[jt * 2 + 1], qf[1], s2[jt], 0, 0, 0);
    }
    __builtin_amdgcn_s_setprio(0);

    // ---- exp2 (scale pre-folded into q) -> pack 4 bf16 -> ds_write_b64
#pragma unroll
    for (int jt = 0; jt < 4; ++jt) {
      const float p0 = exp2f(s2[jt][0]);
      const float p1 = exp2f(s2[jt][1]);
      const float p2 = exp2f(s2[jt][2]);
      const float p3 = exp2f(s2[jt][3]);
      lacc += (p0 + p1) + (p2 + p3);
      unsigned lo, hi;
      asm("v_cvt_pk_bf16_f32 %0, %1, %2" : "=v"(lo) : "v"(p0), "v"(p1));
      asm("v_cvt_pk_bf16_f32 %0, %1, %2" : "=v"(hi) : "v"(p2), "v"(p3));
      int2 w2; w2.x = (int)lo; w2.y = (int)hi;
      const int boff = (jt * 32 + lg * 8) ^ ((l15 & 7) << 4);
      *(int2*)(pw + l15 * 128 + boff) = w2;
    }

    // ---- PV: P frags (row l15) + batch V-frag reads, then MFMAs
    short8v pf[2];
#pragma unroll
    for (int jc = 0; jc < 2; ++jc) {
      const int boff = (jc * 64 + lg * 16) ^ ((l15 & 7) << 4);
      pf[jc] = *(const short8v*)(pw + l15 * 128 + boff);
    }
    short8v vf[8];
#pragma unroll
    for (int dt = 0; dt < 4; ++dt) {
      const int d = dt * 16 + l15;
#pragma unroll
      for (int jc = 0; jc < 2; ++jc) {
        const int j0 = jc * 32 + lg * 8;
        vf[dt * 2 + jc] = *(const short8v*)&Vs[grp][cur][d * 64 + (j0 ^ ((d & 7) << 3))];
      }
    }
    __builtin_amdgcn_s_setprio(1);
#pragma unroll
    for (int dt = 0; dt < 4; ++dt) {
      oacc[dt] = __builtin_amdgcn_mfma_f32_16x16x32_bf16(pf[0], vf[dt * 2 + 0], oacc[dt], 0, 0, 0);
      oacc[dt] = __builtin_amdgcn_mfma_f32_16x16x32_bf16(pf[1], vf[dt * 2 + 1], oacc[dt], 0, 0, 0);
    }
    __builtin_amdgcn_s_setprio(0);

    if (i < 7) {
      *(int4*)&Ks[grp][cur ^ 1][srow0 * 64 + ssw] = nk0;
      *(int4*)&Vs[grp][cur ^ 1][srow0 * 64 + ssw] = nv0;
      *(int4*)&Ks[grp][cur ^ 1][srow1 * 64 + ssw1] = nk1;
      *(int4*)&Vs[grp][cur ^ 1][srow1 * 64 + ssw1] = nv1;
      __syncthreads();
    }
  }

  // full row-sum for row i = l15: reduce over the 4 lg lanes
  lacc += __shfl_xor(lacc, 16);
  lacc += __shfl_xor(lacc, 32);

  // ---- combine group 1 partials into group 0 via LDS (reuse Ks) ----
  __syncthreads();
  float* cb = (float*)&Ks[0][0][0];        // [wv][16][64] f32 = 16 KB
  float* lcb = cb + 4096;                  // [wv][16]
  if (grp == 1) {
#pragma unroll
    for (int r = 0; r < 4; ++r) {
      const int m = lg * 4 + r;
#pragma unroll
      for (int dt = 0; dt < 4; ++dt)
        cb[wv * 1024 + m * 64 + dt * 16 + l15] = oacc[dt][r];
    }
    if (lg == 0) lcb[wv * 16 + l15] = lacc;
  }
  __syncthreads();
  if (grp == 0) {
#pragma unroll
    for (int r = 0; r < 4; ++r) {
      const int m = lg * 4 + r;
#pragma unroll
      for (int dt = 0; dt < 4; ++dt)
        oacc[dt][r] += cb[wv * 1024 + m * 64 + dt * 16 + l15];
    }
    lacc += lcb[wv * 16 + l15];
    const float linv = 1.0f / lacc;        // row i = l15

    // ---- head epilogue (wave-private; hs reuses Ps area) ----
    short* hs = (short*)pw;

#pragma unroll
    for (int r = 0; r < 4; ++r) {
      const int m = lg * 4 + r;
#pragma unroll
      for (int dt = 0; dt < 4; ++dt) {
        const int chunk = (dt * 2 + (l15 >> 3)) ^ (m & 7);
        hs[m * 64 + chunk * 8 + (l15 & 7)] = f2bf(oacc[dt][r]);
      }
    }

    short8v af[2];
#pragma unroll
    for (int dt = 0; dt < 2; ++dt) {
      const int chunk = (dt * 4 + lg) ^ (l15 & 7);
      af[dt] = *(const short8v*)&hs[l15 * 64 + chunk * 8];
    }

    float4v acc1[4];
#pragma unroll
    for (int et = 0; et < 4; ++et) acc1[et] = (float4v)0.0f;
#pragma unroll
    for (int et = 0; et < 4; ++et)
#pragma unroll
      for (int dt = 0; dt < 2; ++dt) {
        const short8v wb = *(const short8v*)&w0pT[(et * 16 + l15) * 64 + dt * 32 + lg * 8];
        acc1[et] = __builtin_amdgcn_mfma_f32_16x16x32_bf16(af[dt], wb, acc1[et], 0, 0, 0);
      }

    float b0v[4];
#pragma unroll
    for (int et = 0; et < 4; ++et) b0v[et] = b0p[et * 16 + l15];

#pragma unroll
    for (int r = 0; r < 4; ++r) {
      const float invm = __shfl(linv, lg * 4 + r);
      const int m = lg * 4 + r;
#pragma unroll
      for (int et = 0; et < 4; ++et) {
        const float v = fmaxf(acc1[et][r] * invm + b0v[et], 0.f);
        const int chunk = (et * 2 + (l15 >> 3)) ^ (m & 7);
        hs[m * 64 + chunk * 8 + (l15 & 7)] = f2bf(v);
      }
    }

    float4v accL = (float4v)0.0f;
#pragma unroll
    for (int dt = 0; dt < 2; ++dt) {
      const int chunk = (dt * 4 + lg) ^ (l15 & 7);
      const short8v ha = *(const short8v*)&hs[l15 * 64 + chunk * 8];
      const short8v wb = *(const short8v*)&wdpT[l15 * 128 + dt * 32 + lg * 8];
      accL = __builtin_amdgcn_mfma_f32_16x16x32_bf16(ha, wb, accL, 0, 0, 0);
    }
    const size_t o2row = ((size_t)bb * TT + qbase + l15) * DD;
#pragma unroll
    for (int dt = 0; dt < 2; ++dt) {
      const short8v ha = *(const short8v*)&o2m[o2row + dt * 32 + lg * 8];
      const short8v wb = *(const short8v*)&wdpT[l15 * 128 + 64 + dt * 32 + lg * 8];
      accL = __builtin_amdgcn_mfma_f32_16x16x32_bf16(ha, wb, accL, 0, 0, 0);
    }

    const float bdv = bdp[l15];
#pragma unroll
    for (int r = 0; r < 4; ++r) {
      const float lv = (l15 < NCLS) ? (accL[r] + bdv) : -1e30f;
      float mx = lv;
#pragma unroll
      for (int off = 1; off < 16; off <<= 1) mx = fmaxf(mx, __shfl_xor(mx, off));
      const float ex = (l15 < NCLS) ? __expf(lv - mx) : 0.f;
      float sm = ex;
#pragma unroll
      for (int off = 1; off < 16; off <<= 1) sm += __shfl_xor(sm, off);
      if (l15 < NCLS)
        out[((size_t)bb * TT + qbase + lg * 4 + r) * NCLS + l15] = ex / sm;
    }
  }
}

// -----------------------------------------------------------------------
extern "C" void kernel_launch(void* const* d_in, const int* in_sizes, int n_in,
                              void* d_out, int out_size, void* d_ws, size_t ws_size,
                              hipStream_t stream) {
  (void)in_sizes; (void)n_in; (void)out_size; (void)ws_size;
  const float* x  = (const float*)d_in[0];
  const float* wq = (const float*)d_in[1];
  const float* wk = (const float*)d_in[2];
  const float* wv = (const float*)d_in[3];
  const float* bn_a_gamma = (const float*)d_in[4];
  const float* bn_a_beta  = (const float*)d_in[5];
  const float* bn_a_mean  = (const float*)d_in[6];
  const float* bn_a_var   = (const float*)d_in[7];
  const float* w0 = (const float*)d_in[8];
  const float* b0 = (const float*)d_in[9];
  const float* w1 = (const float*)d_in[10];
  const float* b1 = (const float*)d_in[11];
  const float* bn1_gamma = (const float*)d_in[12];
  const float* bn1_beta  = (const float*)d_in[13];
  const float* bn1_mean  = (const float*)d_in[14];
  const float* bn1_var   = (const float*)d_in[15];
  const float* wd = (const float*)d_in[16];
  const float* bd = (const float*)d_in[17];
  float* out = (float*)d_out;

  char* cur = (char*)d_ws;
  short* q  = (short*)cur; cur += (size_t)M * DD * 2;
  short* k  = (short*)cur; cur += (size_t)M * DD * 2;
  short* vt = (short*)cur; cur += (size_t)M * DD * 2;
  short* o2 = (short*)cur; cur += (size_t)M * DD * 2;
  short* xbf = (short*)cur; cur += (size_t)M * FF * 2;
  short* wT4  = (short*)cur; cur += 4 * 8192 * 2;
  short* w0pT = (short*)cur; cur += 4096 * 2;
  short* wdpT = (short*)cur; cur += 2048 * 2;
  float* b0p  = (float*)cur; cur += 64 * 4;
  float* bdp  = (float*)cur; cur += 16 * 4;
  float* peq  = (float*)cur; cur += (size_t)TT * DD * 4;
  float* pek  = (float*)cur; cur += (size_t)TT * DD * 4;
  float* pev  = (float*)cur; cur += (size_t)TT * DD * 4;

  prep_kernel<<<dim3(453), dim3(256), 0, stream>>>(
      x, wq, wk, wv, w1, w0, b0, bn_a_gamma, bn_a_beta, bn_a_mean, bn_a_var,
      bn1_gamma, bn1_beta, bn1_mean, bn1_var, wd, bd,
      xbf, wT4, w0pT, b0p, wdpT, bdp, peq, pek, pev);
  proj_kernel<<<dim3(M / 128, 4), dim3(256), 0, stream>>>(
      xbf, wT4, peq, pek, pev, b1, q, k, vt, o2);
  attn_head_kernel<<<dim3(512), dim3(512), 0, stream>>>(
      q, k, vt, o2, w0pT, b0p, wdpT, bdp, out);
}

// Round 16
// 46.523 us; speedup vs baseline: 1.1401x; 1.0804x over previous
//
#include <hip/hip_runtime.h>
#include <math.h>

#define BB 32
#define TT 1024
#define FF 128
#define DD 64
#define NCLS 11
constexpr float kEps = 1e-3f;
constexpr int M = BB * TT;  // 32768 rows

typedef __attribute__((ext_vector_type(8))) short short8v;
typedef __attribute__((ext_vector_type(4))) short short4v;
typedef __attribute__((ext_vector_type(4))) float float4v;

__device__ __forceinline__ short f2bf(float f) {
  union { float f; unsigned u; } v; v.f = f;
  return (short)((v.u + 0x7FFFu + ((v.u >> 16) & 1u)) >> 16);
}
__device__ __forceinline__ float bf2f(short s) {
  union { unsigned u; float f; } v; v.u = ((unsigned)(unsigned short)s) << 16;
  return v.f;
}

// ---- prep: blk 0 folds; 1-4 wT4; 5-196 pe@{wq,wk,wv}; 197+ x->bf16 ----
__global__ __launch_bounds__(256) void prep_kernel(
    const float* __restrict__ x,
    const float* __restrict__ wq, const float* __restrict__ wk,
    const float* __restrict__ wv, const float* __restrict__ w1,
    const float* __restrict__ w0, const float* __restrict__ b0,
    const float* __restrict__ bn_a_gamma, const float* __restrict__ bn_a_beta,
    const float* __restrict__ bn_a_mean, const float* __restrict__ bn_a_var,
    const float* __restrict__ bn1_gamma, const float* __restrict__ bn1_beta,
    const float* __restrict__ bn1_mean, const float* __restrict__ bn1_var,
    const float* __restrict__ wd, const float* __restrict__ bd,
    short* __restrict__ xbf, short* __restrict__ wT4,
    short* __restrict__ w0pT, float* __restrict__ b0p,
    short* __restrict__ wdpT, float* __restrict__ bdp,
    float* __restrict__ peq, float* __restrict__ pek, float* __restrict__ pev) {
  const int t = threadIdx.x;
  const int blk = blockIdx.x;

  if (blk >= 197) {                  // ---- x -> bf16 (row-major copy)
    const int p2 = blk - 197;        // 0..255
    const size_t base = (size_t)p2 * 16384;
#pragma unroll
    for (int i = 0; i < 8; ++i) {
      const size_t e0 = base + (size_t)i * 2048 + (size_t)t * 8;
      const float4 a = *(const float4*)&x[e0];
      const float4 b = *(const float4*)&x[e0 + 4];
      short8v s8;
      s8[0] = f2bf(a.x); s8[1] = f2bf(a.y); s8[2] = f2bf(a.z); s8[3] = f2bf(a.w);
      s8[4] = f2bf(b.x); s8[5] = f2bf(b.y); s8[6] = f2bf(b.z); s8[7] = f2bf(b.w);
      *(short8v*)&xbf[e0] = s8;
    }
    return;
  }
  if (blk >= 5) {                    // ---- pe projection, pe rows on the fly
    __shared__ float peL[16][128];
    const int p = blk - 5;           // 0..191
    const int y = p >> 6;            // 0,1,2
    const int t0 = (p & 63) * 16;
#pragma unroll
    for (int i = 0; i < 8; ++i) {
      const int idx = t + i * 256;   // 0..2047
      const int tr = idx >> 7, f = idx & 127;
      const float div = expf(-logf(10000.0f) * (float)(f & ~1) / (float)FF);
      const float ang = (float)(t0 + tr) * div;
      peL[tr][f] = (f & 1) ? cosf(ang) : sinf(ang);
    }
    __syncthreads();
    const float* w = (y == 0) ? wq : (y == 1) ? wk : wv;
    float* dst = (y == 0) ? peq : (y == 1) ? pek : pev;
    const int tr = t >> 4, dq = t & 15;
    float4 acc = {0.f, 0.f, 0.f, 0.f};
    for (int f = 0; f < FF; ++f) {
      const float pv = peL[tr][f];
      const float4 w4 = *(const float4*)&w[f * 64 + dq * 4];
      acc.x += pv * w4.x; acc.y += pv * w4.y;
      acc.z += pv * w4.z; acc.w += pv * w4.w;
    }
    *(float4*)&dst[(t0 + tr) * 64 + dq * 4] = acc;
    return;
  }
  if (blk > 0) {                     // ---- wT4 staging image
    const int y = blk - 1;
    const float* w = (y == 0) ? wq : (y == 1) ? wk : (y == 2) ? wv : w1;
    short* dst = wT4 + y * 8192;
#pragma unroll
    for (int i = 0; i < 4; ++i) {
      const int idx = t + i * 256;   // 0..1023
      const int n = idx >> 4, c = idx & 15;
      short8v s8;
#pragma unroll
      for (int j = 0; j < 8; ++j) s8[j] = f2bf(w[(c * 8 + j) * 64 + n]);
      *(short8v*)&dst[n * 128 + ((c ^ (n & 7)) << 3)] = s8;
    }
    return;
  }
  // ---- block 0: head folds
  __shared__ float cA[64], cAo[64], c1s[64], c1o[64], c2s[64], c2o[64];
  if (t < 64) {
    const float sA = bn_a_gamma[t] * rsqrtf(bn_a_var[t] + kEps);
    cA[t] = sA; cAo[t] = bn_a_beta[t] - bn_a_mean[t] * sA;
    const float s1 = bn1_gamma[t] * rsqrtf(bn1_var[t] + kEps);
    c1s[t] = s1; c1o[t] = bn1_beta[t] - bn1_mean[t] * s1;
    const float s2 = bn1_gamma[t + 64] * rsqrtf(bn1_var[t + 64] + kEps);
    c2s[t] = s2; c2o[t] = bn1_beta[t + 64] - bn1_mean[t + 64] * s2;
  }
  __syncthreads();
  for (int i = t; i < 4096; i += 256) {
    const int e = i >> 6, k = i & 63;
    w0pT[i] = f2bf(cA[k] * w0[k * 64 + e]);
  }
  if (t < 64) {
    float s = b0[t];
    for (int k = 0; k < 64; ++k) s += cAo[k] * w0[k * 64 + t];
    b0p[t] = s;
  }
  for (int i = t; i < 2048; i += 256) {
    const int c = i >> 7, e = i & 127;
    float v = 0.f;
    if (c < NCLS) v = wd[e * NCLS + c] * (e < 64 ? c1s[e] : c2s[e - 64]);
    wdpT[i] = f2bf(v);
  }
  if (t < 16) {
    float s = 0.f;
    if (t < NCLS) {
      s = bd[t];
      for (int e = 0; e < 64; ++e) s += c1o[e] * wd[e * NCLS + t];
      for (int e = 0; e < 64; ++e) s += c2o[e] * wd[(64 + e) * NCLS + t];
    }
    bdp[t] = s;
  }
}

// --------------------- QKV + out2 projections (bf16 MFMA) --------------
// 64-row tiles: 32KB LDS -> 5 blocks/CU (20 waves/CU) for latency hiding.
// q gets the attention exp scale folded in: q *= log2(e)/8.
__global__ __launch_bounds__(256) void proj_kernel(
    const short* __restrict__ xbf, const short* __restrict__ wT4,
    const float* __restrict__ peq, const float* __restrict__ pek,
    const float* __restrict__ pev, const float* __restrict__ b1,
    short* __restrict__ qo, short* __restrict__ ko,
    short* __restrict__ vt, short* __restrict__ o2) {
  __shared__ __align__(16) short xs[64 * 128];    // [row][k], chunk-swizzled
  __shared__ __align__(16) short wsh[64 * 128];   // [n][k], chunk-swizzled
  const int tid = threadIdx.x;
  const int lane = tid & 63;
  const int wv4 = tid >> 6;
  const int l15 = lane & 15;
  const int lg = lane >> 4;
  const int r0 = blockIdx.x * 64;
  const int y = blockIdx.y;

#pragma unroll
  for (int i = 0; i < 4; ++i) {
    int id = tid + i * 256;          // 0..1023
    int row = id >> 4, chunk = id & 15;
    const int4 v = *(const int4*)&xbf[((size_t)(r0 + row)) * FF + chunk * 8];
    *(int4*)&xs[row * 128 + ((chunk ^ (row & 7)) << 3)] = v;
  }
#pragma unroll
  for (int i = 0; i < 4; ++i) {
    const int idx = tid + i * 256;   // 1024 int4 = 16 KB
    *(int4*)&wsh[idx * 8] = *(const int4*)&wT4[y * 8192 + idx * 8];
  }
  __syncthreads();

  float4v acc[4];
#pragma unroll
  for (int dt = 0; dt < 4; ++dt) acc[dt] = (float4v)0.0f;

  const bool natural = (y == 2);
  const int xrow = wv4 * 16 + l15;
#pragma unroll
  for (int kt = 0; kt < 4; ++kt) {
    const int chunk = kt * 4 + lg;
    const short8v xa = *(const short8v*)&xs[xrow * 128 + ((chunk ^ (xrow & 7)) << 3)];
    short8v wa[4];
#pragma unroll
    for (int dt = 0; dt < 4; ++dt) {
      const int n = dt * 16 + l15;
      wa[dt] = *(const short8v*)&wsh[n * 128 + ((chunk ^ (n & 7)) << 3)];
    }
#pragma unroll
    for (int dt = 0; dt < 4; ++dt)
      acc[dt] = natural
          ? __builtin_amdgcn_mfma_f32_16x16x32_bf16(xa, wa[dt], acc[dt], 0, 0, 0)
          : __builtin_amdgcn_mfma_f32_16x16x32_bf16(wa[dt], xa, acc[dt], 0, 0, 0);
  }

  if (natural) {
    const int bq = r0 >> 10;
    const int t0 = (r0 & 1023) + wv4 * 16 + lg * 4;
#pragma unroll
    for (int dt = 0; dt < 4; ++dt) {
      const int d = dt * 16 + l15;
      short4v s;
#pragma unroll
      for (int r = 0; r < 4; ++r)
        s[r] = f2bf(acc[dt][r] + pev[(t0 + r) * 64 + d]);
      *(short4v*)&vt[((size_t)(bq * DD + d)) * TT + t0] = s;
    }
  } else {
    short* dst = (y == 0) ? qo : (y == 1) ? ko : o2;
    const float* petab = (y == 0) ? peq : pek;
    const float qs = (y == 0) ? 0.18033688f : 1.0f;   // log2(e)/8 folded into q
    const int row = r0 + wv4 * 16 + l15;
    const int tr = row & 1023;
#pragma unroll
    for (int dt = 0; dt < 4; ++dt) {
      const int d0 = dt * 16 + lg * 4;
      float v0 = acc[dt][0], v1 = acc[dt][1];
      float v2 = acc[dt][2], v3 = acc[dt][3];
      if (y == 3) {
        const float4 bv = *(const float4*)&b1[d0];
        v0 = fmaxf(v0 + bv.x, 0.f); v1 = fmaxf(v1 + bv.y, 0.f);
        v2 = fmaxf(v2 + bv.z, 0.f); v3 = fmaxf(v3 + bv.w, 0.f);
      } else {
        const float4 pv = *(const float4*)&petab[tr * 64 + d0];
        v0 = (v0 + pv.x) * qs; v1 = (v1 + pv.y) * qs;
        v2 = (v2 + pv.z) * qs; v3 = (v3 + pv.w) * qs;
      }
      short4v s;
      s[0] = f2bf(v0); s[1] = f2bf(v1); s[2] = f2bf(v2); s[3] = f2bf(v3);
      *(short4v*)&dst[(size_t)row * DD + d0] = s;
    }
  }
}

// --- fused attn + head (best structure + setprio): 8 waves, 2-group
// kv-split, dbuf staging, swapped QK^T (P row lane-local) -> packed b64 P.
// exp scale pre-folded into q. Grid 512 flat, XCD: blockIdx%8 == b%8.
__global__ __launch_bounds__(512, 4) void attn_head_kernel(
    const short* __restrict__ qg, const short* __restrict__ kg,
    const short* __restrict__ vtg, const short* __restrict__ o2m,
    const short* __restrict__ w0pT, const float* __restrict__ b0p,
    const short* __restrict__ wdpT, const float* __restrict__ bdp,
    float* __restrict__ out) {
  __shared__ __align__(16) short Ks[2][2][4096];   // [grp][dbuf][kv*d]
  __shared__ __align__(16) short Vs[2][2][4096];   // [grp][dbuf][d*kv]
  __shared__ __align__(16) short Ps[8 * 1024];     // per-wave P / hs
  const int tid = threadIdx.x;
  const int lane = tid & 63;
  const int wid = tid >> 6;          // 0..7
  const int grp = wid >> 2;          // 0,1
  const int wv = wid & 3;
  const int id = blockIdx.x;
  const int bb = (id & 7) + ((id >> 7) << 3);      // b: id%8 fixes XCD
  const int qx = (id >> 3) & 15;
  const int l15 = lane & 15;
  const int lg = lane >> 4;          // 0..3
  const int qbase = qx * 64 + wv * 16;
  const int kt0 = grp * 8;

  const int stid = tid & 255;
  const int srow0 = stid >> 3, sc8 = (stid & 7) * 8;
  const int ssw = sc8 ^ ((srow0 & 7) << 3);
  const int srow1 = srow0 + 32;
  const int ssw1 = sc8 ^ ((srow1 & 7) << 3);

  short8v qf[2];
#pragma unroll
  for (int dt = 0; dt < 2; ++dt) {
    const size_t off = ((size_t)(bb * TT + qbase + l15)) * DD + dt * 32 + lg * 8;
    qf[dt] = *(const short8v*)&qg[off];
  }
  float4v oacc[4];
#pragma unroll
  for (int dt = 0; dt < 4; ++dt) oacc[dt] = (float4v)0.0f;
  float lacc = 0.f;                  // row i = l15 partial sum

  // prologue: stage this group's tile 0 into buf 0
  {
    const int nt = kt0 * 64;
    const int4 k0 = *(const int4*)&kg[((size_t)(bb * TT + nt + srow0)) * DD + sc8];
    const int4 v0 = *(const int4*)&vtg[((size_t)(bb * DD + srow0)) * TT + nt + sc8];
    const int4 k1 = *(const int4*)&kg[((size_t)(bb * TT + nt + srow1)) * DD + sc8];
    const int4 v1 = *(const int4*)&vtg[((size_t)(bb * DD + srow1)) * TT + nt + sc8];
    *(int4*)&Ks[grp][0][srow0 * 64 + ssw] = k0;
    *(int4*)&Vs[grp][0][srow0 * 64 + ssw] = v0;
    *(int4*)&Ks[grp][0][srow1 * 64 + ssw1] = k1;
    *(int4*)&Vs[grp][0][srow1 * 64 + ssw1] = v1;
  }
  __syncthreads();

  char* const pw = (char*)&Ps[wid * 1024];   // this wave's 2KB P area
  for (int i = 0; i < 8; ++i) {
    const int cur = i & 1;

    int4 nk0, nv0, nk1, nv1;
    if (i < 7) {
      const int nt = (kt0 + i + 1) * 64;
      nk0 = *(const int4*)&kg[((size_t)(bb * TT + nt + srow0)) * DD + sc8];
      nv0 = *(const int4*)&vtg[((size_t)(bb * DD + srow0)) * TT + nt + sc8];
      nk1 = *(const int4*)&kg[((size_t)(bb * TT + nt + srow1)) * DD + sc8];
      nv1 = *(const int4*)&vtg[((size_t)(bb * DD + srow1)) * TT + nt + sc8];
    }

    // ---- QK^T swapped: A=K, B=Q -> lane holds P[i=l15][j=jt*16+lg*4+r]
    short8v kf[8];
#pragma unroll
    for (int jt = 0; jt < 4; ++jt) {
      const int j = jt * 16 + l15;
#pragma unroll
      for (int dt = 0; dt < 2; ++dt) {
        const int d0 = dt * 32 + lg * 8;
        kf[jt * 2 + dt] = *(const short8v*)&Ks[grp][cur][j * 64 + (d0 ^ ((j & 7) << 3))];
      }
    }
    float4v s2[4];
    __builtin_amdgcn_s_setprio(1);
#pragma unroll
    for (int jt = 0; jt < 4; ++jt) {
      s2[jt] = (float4v)0.0f;
      s2[jt] = __builtin_amdgcn_mfma_f32_16x16x32_bf16(kf[jt * 2 + 0], qf[0], s2[jt], 0, 0, 0);
      s2[jt] = __builtin_amdgcn_mfma_f32_16x16x32_bf16(kf[jt * 2 + 1], qf[1], s2[jt], 0, 0, 0);
    }
    __builtin_amdgcn_s_setprio(0);

    // ---- exp2 (scale pre-folded into q) -> pack 4 bf16 -> ds_write_b64
#pragma unroll
    for (int jt = 0; jt < 4; ++jt) {
      const float p0 = exp2f(s2[jt][0]);
      const float p1 = exp2f(s2[jt][1]);
      const float p2 = exp2f(s2[jt][2]);
      const float p3 = exp2f(s2[jt][3]);
      lacc += (p0 + p1) + (p2 + p3);
      unsigned lo, hi;
      asm("v_cvt_pk_bf16_f32 %0, %1, %2" : "=v"(lo) : "v"(p0), "v"(p1));
      asm("v_cvt_pk_bf16_f32 %0, %1, %2" : "=v"(hi) : "v"(p2), "v"(p3));
      int2 w2; w2.x = (int)lo; w2.y = (int)hi;
      const int boff = (jt * 32 + lg * 8) ^ ((l15 & 7) << 4);
      *(int2*)(pw + l15 * 128 + boff) = w2;
    }

    // ---- PV: P frags (row l15) + batch V-frag reads, then MFMAs
    short8v pf[2];
#pragma unroll
    for (int jc = 0; jc < 2; ++jc) {
      const int boff = (jc * 64 + lg * 16) ^ ((l15 & 7) << 4);
      pf[jc] = *(const short8v*)(pw + l15 * 128 + boff);
    }
    short8v vf[8];
#pragma unroll
    for (int dt = 0; dt < 4; ++dt) {
      const int d = dt * 16 + l15;
#pragma unroll
      for (int jc = 0; jc < 2; ++jc) {
        const int j0 = jc * 32 + lg * 8;
        vf[dt * 2 + jc] = *(const short8v*)&Vs[grp][cur][d * 64 + (j0 ^ ((d & 7) << 3))];
      }
    }
    __builtin_amdgcn_s_setprio(1);
#pragma unroll
    for (int dt = 0; dt < 4; ++dt) {
      oacc[dt] = __builtin_amdgcn_mfma_f32_16x16x32_bf16(pf[0], vf[dt * 2 + 0], oacc[dt], 0, 0, 0);
      oacc[dt] = __builtin_amdgcn_mfma_f32_16x16x32_bf16(pf[1], vf[dt * 2 + 1], oacc[dt], 0, 0, 0);
    }
    __builtin_amdgcn_s_setprio(0);

    if (i < 7) {
      *(int4*)&Ks[grp][cur ^ 1][srow0 * 64 + ssw] = nk0;
      *(int4*)&Vs[grp][cur ^ 1][srow0 * 64 + ssw] = nv0;
      *(int4*)&Ks[grp][cur ^ 1][srow1 * 64 + ssw1] = nk1;
      *(int4*)&Vs[grp][cur ^ 1][srow1 * 64 + ssw1] = nv1;
      __syncthreads();
    }
  }

  // full row-sum for row i = l15: reduce over the 4 lg lanes
  lacc += __shfl_xor(lacc, 16);
  lacc += __shfl_xor(lacc, 32);

  // ---- combine group 1 partials into group 0 via LDS (reuse Ks) ----
  __syncthreads();
  float* cb = (float*)&Ks[0][0][0];        // [wv][16][64] f32 = 16 KB
  float* lcb = cb + 4096;                  // [wv][16]
  if (grp == 1) {
#pragma unroll
    for (int r = 0; r < 4; ++r) {
      const int m = lg * 4 + r;
#pragma unroll
      for (int dt = 0; dt < 4; ++dt)
        cb[wv * 1024 + m * 64 + dt * 16 + l15] = oacc[dt][r];
    }
    if (lg == 0) lcb[wv * 16 + l15] = lacc;
  }
  __syncthreads();
  if (grp == 0) {
#pragma unroll
    for (int r = 0; r < 4; ++r) {
      const int m = lg * 4 + r;
#pragma unroll
      for (int dt = 0; dt < 4; ++dt)
        oacc[dt][r] += cb[wv * 1024 + m * 64 + dt * 16 + l15];
    }
    lacc += lcb[wv * 16 + l15];
    const float linv = 1.0f / lacc;        // row i = l15

    // ---- head epilogue (wave-private; hs reuses Ps area) ----
    short* hs = (short*)pw;

#pragma unroll
    for (int r = 0; r < 4; ++r) {
      const int m = lg * 4 + r;
#pragma unroll
      for (int dt = 0; dt < 4; ++dt) {
        const int chunk = (dt * 2 + (l15 >> 3)) ^ (m & 7);
        hs[m * 64 + chunk * 8 + (l15 & 7)] = f2bf(oacc[dt][r]);
      }
    }

    short8v af[2];
#pragma unroll
    for (int dt = 0; dt < 2; ++dt) {
      const int chunk = (dt * 4 + lg) ^ (l15 & 7);
      af[dt] = *(const short8v*)&hs[l15 * 64 + chunk * 8];
    }

    float4v acc1[4];
#pragma unroll
    for (int et = 0; et < 4; ++et) acc1[et] = (float4v)0.0f;
#pragma unroll
    for (int et = 0; et < 4; ++et)
#pragma unroll
      for (int dt = 0; dt < 2; ++dt) {
        const short8v wb = *(const short8v*)&w0pT[(et * 16 + l15) * 64 + dt * 32 + lg * 8];
        acc1[et] = __builtin_amdgcn_mfma_f32_16x16x32_bf16(af[dt], wb, acc1[et], 0, 0, 0);
      }

    float b0v[4];
#pragma unroll
    for (int et = 0; et < 4; ++et) b0v[et] = b0p[et * 16 + l15];

#pragma unroll
    for (int r = 0; r < 4; ++r) {
      const float invm = __shfl(linv, lg * 4 + r);
      const int m = lg * 4 + r;
#pragma unroll
      for (int et = 0; et < 4; ++et) {
        const float v = fmaxf(acc1[et][r] * invm + b0v[et], 0.f);
        const int chunk = (et * 2 + (l15 >> 3)) ^ (m & 7);
        hs[m * 64 + chunk * 8 + (l15 & 7)] = f2bf(v);
      }
    }

    float4v accL = (float4v)0.0f;
#pragma unroll
    for (int dt = 0; dt < 2; ++dt) {
      const int chunk = (dt * 4 + lg) ^ (l15 & 7);
      const short8v ha = *(const short8v*)&hs[l15 * 64 + chunk * 8];
      const short8v wb = *(const short8v*)&wdpT[l15 * 128 + dt * 32 + lg * 8];
      accL = __builtin_amdgcn_mfma_f32_16x16x32_bf16(ha, wb, accL, 0, 0, 0);
    }
    const size_t o2row = ((size_t)bb * TT + qbase + l15) * DD;
#pragma unroll
    for (int dt = 0; dt < 2; ++dt) {
      const short8v ha = *(const short8v*)&o2m[o2row + dt * 32 + lg * 8];
      const short8v wb = *(const short8v*)&wdpT[l15 * 128 + 64 + dt * 32 + lg * 8];
      accL = __builtin_amdgcn_mfma_f32_16x16x32_bf16(ha, wb, accL, 0, 0, 0);
    }

    const float bdv = bdp[l15];
#pragma unroll
    for (int r = 0; r < 4; ++r) {
      const float lv = (l15 < NCLS) ? (accL[r] + bdv) : -1e30f;
      float mx = lv;
#pragma unroll
      for (int off = 1; off < 16; off <<= 1) mx = fmaxf(mx, __shfl_xor(mx, off));
      const float ex = (l15 < NCLS) ? __expf(lv - mx) : 0.f;
      float sm = ex;
#pragma unroll
      for (int off = 1; off < 16; off <<= 1) sm += __shfl_xor(sm, off);
      if (l15 < NCLS)
        out[((size_t)bb * TT + qbase + lg * 4 + r) * NCLS + l15] = ex / sm;
    }
  }
}

// -----------------------------------------------------------------------
extern "C" void kernel_launch(void* const* d_in, const int* in_sizes, int n_in,
                              void* d_out, int out_size, void* d_ws, size_t ws_size,
                              hipStream_t stream) {
  (void)in_sizes; (void)n_in; (void)out_size; (void)ws_size;
  const float* x  = (const float*)d_in[0];
  const float* wq = (const float*)d_in[1];
  const float* wk = (const float*)d_in[2];
  const float* wv = (const float*)d_in[3];
  const float* bn_a_gamma = (const float*)d_in[4];
  const float* bn_a_beta  = (const float*)d_in[5];
  const float* bn_a_mean  = (const float*)d_in[6];
  const float* bn_a_var   = (const float*)d_in[7];
  const float* w0 = (const float*)d_in[8];
  const float* b0 = (const float*)d_in[9];
  const float* w1 = (const float*)d_in[10];
  const float* b1 = (const float*)d_in[11];
  const float* bn1_gamma = (const float*)d_in[12];
  const float* bn1_beta  = (const float*)d_in[13];
  const float* bn1_mean  = (const float*)d_in[14];
  const float* bn1_var   = (const float*)d_in[15];
  const float* wd = (const float*)d_in[16];
  const float* bd = (const float*)d_in[17];
  float* out = (float*)d_out;

  char* cur = (char*)d_ws;
  short* q  = (short*)cur; cur += (size_t)M * DD * 2;
  short* k  = (short*)cur; cur += (size_t)M * DD * 2;
  short* vt = (short*)cur; cur += (size_t)M * DD * 2;
  short* o2 = (short*)cur; cur += (size_t)M * DD * 2;
  short* xbf = (short*)cur; cur += (size_t)M * FF * 2;
  short* wT4  = (short*)cur; cur += 4 * 8192 * 2;
  short* w0pT = (short*)cur; cur += 4096 * 2;
  short* wdpT = (short*)cur; cur += 2048 * 2;
  float* b0p  = (float*)cur; cur += 64 * 4;
  float* bdp  = (float*)cur; cur += 16 * 4;
  float* peq  = (float*)cur; cur += (size_t)TT * DD * 4;
  float* pek  = (float*)cur; cur += (size_t)TT * DD * 4;
  float* pev  = (float*)cur; cur += (size_t)TT * DD * 4;

  prep_kernel<<<dim3(453), dim3(256), 0, stream>>>(
      x, wq, wk, wv, w1, w0, b0, bn_a_gamma, bn_a_beta, bn_a_mean, bn_a_var,
      bn1_gamma, bn1_beta, bn1_mean, bn1_var, wd, bd,
      xbf, wT4, w0pT, b0p, wdpT, bdp, peq, pek, pev);
  proj_kernel<<<dim3(M / 64, 4), dim3(256), 0, stream>>>(
      xbf, wT4, peq, pek, pev, b1, q, k, vt, o2);
  attn_head_kernel<<<dim3(512), dim3(512), 0, stream>>>(
      q, k, vt, o2, w0pT, b0p, wdpT, bdp, out);
}